// Round 1
// baseline (642.720 us; speedup 1.0000x reference)
//
#include <hip/hip_runtime.h>

#define NJ 24
#define EPSF 1e-8f

// parent indices (compile-time constants; loop fully unrolled)
__device__ __constant__ static const int kParents[NJ] =
    {-1, 0, 0, 0, 1, 2, 3, 4, 5, 6, 7, 8, 9, 9, 9, 12, 13, 14, 16, 17, 18, 19, 20, 21};

// host-side copy for templated unroll (we use a constexpr array instead)
static __device__ __forceinline__ int parent_of(int i) {
    constexpr int P[NJ] = {-1, 0, 0, 0, 1, 2, 3, 4, 5, 6, 7, 8, 9, 9, 9, 12, 13, 14, 16, 17, 18, 19, 20, 21};
    return P[i];
}

__global__ __launch_bounds__(256)
void poseaug_kernel(const float* __restrict__ poses_3d,  // B,24,3
                    const float* __restrict__ rot_mats,  // B,24,3,3
                    const float* __restrict__ axis,      // B,24,3
                    const float* __restrict__ angle_u,   // B,24
                    const float* __restrict__ scale_u,   // B,24
                    const float* __restrict__ Kin,       // B,3,3
                    const float* __restrict__ Rin,       // B,3,3
                    const float* __restrict__ tin,       // B,3
                    const float* __restrict__ focal_u,   // B,2
                    const float* __restrict__ yaw_u,     // B
                    const float* __restrict__ pitch_u,   // B
                    const float* __restrict__ t_jit,     // B,3
                    float* __restrict__ out, int B)
{
    int b = blockIdx.x * blockDim.x + threadIdx.x;
    if (b >= B) return;

    // output layout: concat of [poses(B*72), poses_2d(B*48), rots(B*216), K_aug(B*9), R_aug(B*9), t_aug(B*3)]
    float* out_poses = out;
    float* out_2d    = out + (size_t)B * 72;
    float* out_rots  = out + (size_t)B * 120;
    float* out_K     = out + (size_t)B * 336;
    float* out_R     = out + (size_t)B * 345;
    float* out_t     = out + (size_t)B * 354;

    // ---- load poses (72 floats, 16B-aligned base) ----
    float pf[72];
    const float* pb = poses_3d + (size_t)b * 72;
    #pragma unroll
    for (int i = 0; i < 18; ++i) {
        float4 v = reinterpret_cast<const float4*>(pb)[i];
        pf[4*i+0] = v.x; pf[4*i+1] = v.y; pf[4*i+2] = v.z; pf[4*i+3] = v.w;
    }

    const float* axb = axis     + (size_t)b * 72;
    const float* aub = angle_u  + (size_t)b * 24;
    const float* sub = scale_u  + (size_t)b * 24;
    const float* rmb = rot_mats + (size_t)b * 216;
    float*       rob = out_rots + (size_t)b * 216;

    // joint 0: rots passthrough
    {
        float4 v0 = reinterpret_cast<const float4*>(rmb)[0];
        float4 v1 = reinterpret_cast<const float4*>(rmb)[1];
        reinterpret_cast<float4*>(rob)[0] = v0;
        reinterpret_cast<float4*>(rob)[1] = v1;
        rob[8] = rmb[8];
    }

    // ---- kinematic chain ----
    #pragma unroll
    for (int i = 1; i < NJ; ++i) {
        const int par = parent_of(i);

        float bx = pf[3*i+0] - pf[3*par+0];
        float by = pf[3*i+1] - pf[3*par+1];
        float bz = pf[3*i+2] - pf[3*par+2];
        float blen = sqrtf(bx*bx + by*by + bz*bz);

        float ax = axb[3*i+0], ay = axb[3*i+1], az = axb[3*i+2];
        float n1 = sqrtf(ax*ax + ay*ay + az*az) + EPSF;
        ax /= n1; ay /= n1; az /= n1;
        // _rodrigues normalizes again
        float n2 = sqrtf(ax*ax + ay*ay + az*az) + EPSF;
        ax /= n2; ay /= n2; az /= n2;

        float ang = (aub[i] * 2.0f - 1.0f) * 0.2f;
        float c = cosf(ang), s = sinf(ang);
        float oc = 1.0f - c;

        // Ra = I + s*K + (1-c)*(outer - I)
        float r00 = 1.0f + oc * (ax*ax - 1.0f);
        float r01 = -s*az + oc * ax*ay;
        float r02 =  s*ay + oc * ax*az;
        float r10 =  s*az + oc * ax*ay;
        float r11 = 1.0f + oc * (ay*ay - 1.0f);
        float r12 = -s*ax + oc * ay*az;
        float r20 = -s*ay + oc * ax*az;
        float r21 =  s*ax + oc * ay*az;
        float r22 = 1.0f + oc * (az*az - 1.0f);

        float rbx = r00*bx + r01*by + r02*bz;
        float rby = r10*bx + r11*by + r12*bz;
        float rbz = r20*bx + r21*by + r22*bz;

        float scale = 1.0f + (sub[i] * 2.0f - 1.0f) * 0.1f;
        float rn = sqrtf(rbx*rbx + rby*rby + rbz*rbz) + EPSF;
        float f = scale * blen / rn;

        pf[3*i+0] = pf[3*par+0] + rbx * f;
        pf[3*i+1] = pf[3*par+1] + rby * f;
        pf[3*i+2] = pf[3*par+2] + rbz * f;

        // rots[i] = rot_mats[i] @ Ra
        const float* m = rmb + i * 9;
        float m00=m[0],m01=m[1],m02=m[2],m10=m[3],m11=m[4],m12=m[5],m20=m[6],m21=m[7],m22=m[8];
        float* o = rob + i * 9;
        o[0] = m00*r00 + m01*r10 + m02*r20;
        o[1] = m00*r01 + m01*r11 + m02*r21;
        o[2] = m00*r02 + m01*r12 + m02*r22;
        o[3] = m10*r00 + m11*r10 + m12*r20;
        o[4] = m10*r01 + m11*r11 + m12*r21;
        o[5] = m10*r02 + m11*r12 + m12*r22;
        o[6] = m20*r00 + m21*r10 + m22*r20;
        o[7] = m20*r01 + m21*r11 + m22*r21;
        o[8] = m20*r02 + m21*r12 + m22*r22;
    }

    // ---- store poses ----
    {
        float* po = out_poses + (size_t)b * 72;
        #pragma unroll
        for (int i = 0; i < 18; ++i) {
            float4 v = make_float4(pf[4*i+0], pf[4*i+1], pf[4*i+2], pf[4*i+3]);
            reinterpret_cast<float4*>(po)[i] = v;
        }
    }

    // ---- camera ----
    const float* kb = Kin + (size_t)b * 9;
    const float* rb_ = Rin + (size_t)b * 9;
    float K00=kb[0],K01=kb[1],K02=kb[2],K10=kb[3],K11=kb[4],K12=kb[5],K20=kb[6],K21=kb[7],K22=kb[8];
    float f0 = focal_u[(size_t)b*2+0], f1 = focal_u[(size_t)b*2+1];
    float fs0 = 1.0f + (f0*2.0f - 1.0f) * 0.1f * 0.1f;
    float fs1 = 1.0f + (f1*2.0f - 1.0f) * 0.1f * 0.1f;
    K00 *= fs0; K11 *= fs1;

    float yaw   = (yaw_u[b]   * 2.0f - 1.0f) * 0.1f * 0.1f;
    float pitch = (pitch_u[b] * 2.0f - 1.0f) * 0.1f * 0.05f;
    float cy = cosf(yaw),  sy = sinf(yaw);
    float cp = cosf(pitch), sp = sinf(pitch);

    // M = R_yaw @ R_pitch
    float M00 = cy,   M01 = sy*sp, M02 = sy*cp;
    float M10 = 0.0f, M11 = cp,    M12 = -sp;
    float M20 = -sy,  M21 = cy*sp, M22 = cy*cp;

    float R00=rb_[0],R01=rb_[1],R02=rb_[2],R10=rb_[3],R11=rb_[4],R12=rb_[5],R20=rb_[6],R21=rb_[7],R22=rb_[8];
    float A00 = R00*M00 + R01*M10 + R02*M20;
    float A01 = R00*M01 + R01*M11 + R02*M21;
    float A02 = R00*M02 + R01*M12 + R02*M22;
    float A10 = R10*M00 + R11*M10 + R12*M20;
    float A11 = R10*M01 + R11*M11 + R12*M21;
    float A12 = R10*M02 + R11*M12 + R12*M22;
    float A20 = R20*M00 + R21*M10 + R22*M20;
    float A21 = R20*M01 + R21*M11 + R22*M21;
    float A22 = R20*M02 + R21*M12 + R22*M22;

    float tx = tin[(size_t)b*3+0] + t_jit[(size_t)b*3+0] * 0.1f * 0.05f;
    float ty = tin[(size_t)b*3+1] + t_jit[(size_t)b*3+1] * 0.1f * 0.05f;
    float tz = tin[(size_t)b*3+2] + t_jit[(size_t)b*3+2] * 0.1f * 0.05f;

    // K_aug / R_aug / t_aug outputs
    {
        float* ok = out_K + (size_t)b * 9;
        ok[0]=K00; ok[1]=K01; ok[2]=K02; ok[3]=K10; ok[4]=K11; ok[5]=K12; ok[6]=K20; ok[7]=K21; ok[8]=K22;
        float* orr = out_R + (size_t)b * 9;
        orr[0]=A00; orr[1]=A01; orr[2]=A02; orr[3]=A10; orr[4]=A11; orr[5]=A12; orr[6]=A20; orr[7]=A21; orr[8]=A22;
        float* ot = out_t + (size_t)b * 3;
        ot[0]=tx; ot[1]=ty; ot[2]=tz;
    }

    // projection
    {
        float* o2 = out_2d + (size_t)b * 48;
        #pragma unroll
        for (int n = 0; n < NJ; ++n) {
            float px = pf[3*n+0], py = pf[3*n+1], pz = pf[3*n+2];
            float cx = A00*px + A01*py + A02*pz + tx;
            float cyv = A10*px + A11*py + A12*pz + ty;
            float cz = A20*px + A21*py + A22*pz + tz;
            float zc = fmaxf(cz, 1e-5f);
            float u = K00 * (cx / zc) + K02;
            float v = K11 * (cyv / zc) + K12;
            float2 uv = make_float2(u / 512.0f * 2.0f - 1.0f, v / 512.0f * 2.0f - 1.0f);
            reinterpret_cast<float2*>(o2)[n] = uv;
        }
    }
}

extern "C" void kernel_launch(void* const* d_in, const int* in_sizes, int n_in,
                              void* d_out, int out_size, void* d_ws, size_t ws_size,
                              hipStream_t stream) {
    const float* poses_3d = (const float*)d_in[0];
    const float* rot_mats = (const float*)d_in[1];
    const float* axis     = (const float*)d_in[2];
    const float* angle_u  = (const float*)d_in[3];
    const float* scale_u  = (const float*)d_in[4];
    const float* Kin      = (const float*)d_in[5];
    const float* Rin      = (const float*)d_in[6];
    const float* tin      = (const float*)d_in[7];
    const float* focal_u  = (const float*)d_in[8];
    const float* yaw_u    = (const float*)d_in[9];
    const float* pitch_u  = (const float*)d_in[10];
    const float* t_jit    = (const float*)d_in[11];
    float* out = (float*)d_out;

    int B = in_sizes[9];  // yaw_u is (B,)
    dim3 block(256);
    dim3 grid((B + 255) / 256);
    hipLaunchKernelGGL(poseaug_kernel, grid, block, 0, stream,
                       poses_3d, rot_mats, axis, angle_u, scale_u,
                       Kin, Rin, tin, focal_u, yaw_u, pitch_u, t_jit, out, B);
}

// Round 2
// 405.732 us; speedup vs baseline: 1.5841x; 1.5841x over previous
//
#include <hip/hip_runtime.h>

#define NJ 24
#define EPSF 1e-8f

static __device__ __forceinline__ int parent_of(int i) {
    constexpr int P[NJ] = {-1, 0, 0, 0, 1, 2, 3, 4, 5, 6, 7, 8, 9, 9, 9, 12, 13, 14, 16, 17, 18, 19, 20, 21};
    return P[i];
}

// Rodrigues matrix from raw axis + angle_u (matches reference's double-normalize).
static __device__ __forceinline__ void make_Ra(float ax, float ay, float az, float au, float R[9]) {
    float n1 = sqrtf(ax*ax + ay*ay + az*az) + EPSF;
    ax /= n1; ay /= n1; az /= n1;
    float n2 = sqrtf(ax*ax + ay*ay + az*az) + EPSF;   // reference normalizes twice
    ax /= n2; ay /= n2; az /= n2;
    float ang = (au * 2.0f - 1.0f) * 0.2f;
    float c = cosf(ang), s = sinf(ang), oc = 1.0f - c;
    R[0] = 1.0f + oc*(ax*ax - 1.0f); R[1] = -s*az + oc*ax*ay;        R[2] =  s*ay + oc*ax*az;
    R[3] =  s*az + oc*ax*ay;         R[4] = 1.0f + oc*(ay*ay - 1.0f); R[5] = -s*ax + oc*ay*az;
    R[6] = -s*ay + oc*ax*az;         R[7] =  s*ax + oc*ay*az;         R[8] = 1.0f + oc*(az*az - 1.0f);
}

// ================== Kernel 1: chain + camera + projection ==================
// one wave per block; LDS transpose staging (stride 73, coprime w/ 32 banks)
__global__ __launch_bounds__(64)
void poseaug_chain_kernel(const float* __restrict__ poses_3d,
                          const float* __restrict__ axis,
                          const float* __restrict__ angle_u,
                          const float* __restrict__ scale_u,
                          const float* __restrict__ Kin,
                          const float* __restrict__ Rin,
                          const float* __restrict__ tin,
                          const float* __restrict__ focal_u,
                          const float* __restrict__ yaw_u,
                          const float* __restrict__ pitch_u,
                          const float* __restrict__ t_jit,
                          float* __restrict__ out, int B)
{
    __shared__ __align__(16) float stg[64 * 73];   // 18688 B
    const int l  = threadIdx.x;
    const int e0 = blockIdx.x * 64;
    const int n  = min(64, B - e0);
    const int b  = e0 + l;
    const bool act = (b < B);

    float* out_poses = out;
    float* out_2d    = out + (size_t)B * 72;
    float* out_K     = out + (size_t)B * 336;
    float* out_R     = out + (size_t)B * 345;
    float* out_t     = out + (size_t)B * 354;

    // ---- stage poses: coalesced global -> stride-73 LDS ----
    {
        const float* g = poses_3d + (size_t)e0 * 72;
        if (n == 64) {
            const float4* g4 = (const float4*)g;
            #pragma unroll
            for (int it = 0; it < 18; ++it) {
                int i4 = l + it * 64;
                float4 v = g4[i4];
                int o = i4 * 4;
                int base = (o / 72) * 73 + (o % 72);
                stg[base] = v.x; stg[base+1] = v.y; stg[base+2] = v.z; stg[base+3] = v.w;
            }
        } else {
            for (int o = l; o < n * 72; o += 64) stg[(o / 72) * 73 + (o % 72)] = g[o];
        }
    }
    __syncthreads();
    float pf[72];
    #pragma unroll
    for (int k = 0; k < 72; ++k) pf[k] = stg[l * 73 + k];
    __syncthreads();

    // ---- stage axis (stays in LDS for chain) ----
    {
        const float* g = axis + (size_t)e0 * 72;
        if (n == 64) {
            const float4* g4 = (const float4*)g;
            #pragma unroll
            for (int it = 0; it < 18; ++it) {
                int i4 = l + it * 64;
                float4 v = g4[i4];
                int o = i4 * 4;
                int base = (o / 72) * 73 + (o % 72);
                stg[base] = v.x; stg[base+1] = v.y; stg[base+2] = v.z; stg[base+3] = v.w;
            }
        } else {
            for (int o = l; o < n * 72; o += 64) stg[(o / 72) * 73 + (o % 72)] = g[o];
        }
    }
    __syncthreads();

    // ---- angle/scale: back-to-back float4 loads into registers ----
    float au[24], su[24];
    if (act) {
        const float4* ga = (const float4*)(angle_u + (size_t)b * 24);
        const float4* gs = (const float4*)(scale_u + (size_t)b * 24);
        #pragma unroll
        for (int q = 0; q < 6; ++q) {
            float4 va = ga[q]; au[4*q+0]=va.x; au[4*q+1]=va.y; au[4*q+2]=va.z; au[4*q+3]=va.w;
            float4 vs = gs[q]; su[4*q+0]=vs.x; su[4*q+1]=vs.y; su[4*q+2]=vs.z; su[4*q+3]=vs.w;
        }
    }

    // ---- kinematic chain ----
    #pragma unroll
    for (int i = 1; i < NJ; ++i) {
        const int par = parent_of(i);
        float bx = pf[3*i+0] - pf[3*par+0];
        float by = pf[3*i+1] - pf[3*par+1];
        float bz = pf[3*i+2] - pf[3*par+2];
        float blen = sqrtf(bx*bx + by*by + bz*bz);

        float Ra[9];
        make_Ra(stg[l*73 + 3*i + 0], stg[l*73 + 3*i + 1], stg[l*73 + 3*i + 2], au[i], Ra);

        float rbx = Ra[0]*bx + Ra[1]*by + Ra[2]*bz;
        float rby = Ra[3]*bx + Ra[4]*by + Ra[5]*bz;
        float rbz = Ra[6]*bx + Ra[7]*by + Ra[8]*bz;

        float scale = 1.0f + (su[i] * 2.0f - 1.0f) * 0.1f;
        float rn = sqrtf(rbx*rbx + rby*rby + rbz*rbz) + EPSF;
        float f = scale * blen / rn;

        pf[3*i+0] = pf[3*par+0] + rbx * f;
        pf[3*i+1] = pf[3*par+1] + rby * f;
        pf[3*i+2] = pf[3*par+2] + rbz * f;
    }

    // ---- camera ----
    float K00, K02, K11, K12, Kf[9];
    float A[9], tx = 0.f, ty = 0.f, tz = 0.f;
    if (act) {
        const float* kb = Kin + (size_t)b * 9;
        const float* rb = Rin + (size_t)b * 9;
        #pragma unroll
        for (int k = 0; k < 9; ++k) Kf[k] = kb[k];
        float f0 = focal_u[(size_t)b*2+0], f1 = focal_u[(size_t)b*2+1];
        Kf[0] *= 1.0f + (f0*2.0f - 1.0f) * 0.01f;
        Kf[4] *= 1.0f + (f1*2.0f - 1.0f) * 0.01f;
        K00 = Kf[0]; K02 = Kf[2]; K11 = Kf[4]; K12 = Kf[5];

        float yaw   = (yaw_u[b]   * 2.0f - 1.0f) * 0.01f;
        float pitch = (pitch_u[b] * 2.0f - 1.0f) * 0.005f;
        float cy = cosf(yaw),  sy = sinf(yaw);
        float cp = cosf(pitch), sp = sinf(pitch);
        float M00 = cy,   M01 = sy*sp, M02 = sy*cp;
        float M11 = cp,   M12 = -sp;
        float M20 = -sy,  M21 = cy*sp, M22 = cy*cp;

        float R00=rb[0],R01=rb[1],R02=rb[2],R10=rb[3],R11=rb[4],R12=rb[5],R20=rb[6],R21=rb[7],R22=rb[8];
        A[0] = R00*M00 + R02*M20; A[1] = R00*M01 + R01*M11 + R02*M21; A[2] = R00*M02 + R01*M12 + R02*M22;
        A[3] = R10*M00 + R12*M20; A[4] = R10*M01 + R11*M11 + R12*M21; A[5] = R10*M02 + R11*M12 + R12*M22;
        A[6] = R20*M00 + R22*M20; A[7] = R20*M01 + R21*M11 + R22*M21; A[8] = R20*M02 + R21*M12 + R22*M22;

        tx = tin[(size_t)b*3+0] + t_jit[(size_t)b*3+0] * 0.005f;
        ty = tin[(size_t)b*3+1] + t_jit[(size_t)b*3+1] * 0.005f;
        tz = tin[(size_t)b*3+2] + t_jit[(size_t)b*3+2] * 0.005f;

        // small outputs: direct stores (contiguous 36/36/12-B segments)
        float* ok = out_K + (size_t)b * 9;
        #pragma unroll
        for (int k = 0; k < 9; ++k) ok[k] = Kf[k];
        float* orr = out_R + (size_t)b * 9;
        #pragma unroll
        for (int k = 0; k < 9; ++k) orr[k] = A[k];
        float* ot = out_t + (size_t)b * 3;
        ot[0] = tx; ot[1] = ty; ot[2] = tz;
    }

    // ---- store poses via LDS transpose ----
    __syncthreads();
    #pragma unroll
    for (int k = 0; k < 72; ++k) stg[l * 73 + k] = pf[k];
    __syncthreads();
    {
        float* g = out_poses + (size_t)e0 * 72;
        if (n == 64) {
            float4* g4 = (float4*)g;
            #pragma unroll
            for (int it = 0; it < 18; ++it) {
                int i4 = l + it * 64;
                int o = i4 * 4;
                int base = (o / 72) * 73 + (o % 72);
                g4[i4] = make_float4(stg[base], stg[base+1], stg[base+2], stg[base+3]);
            }
        } else {
            for (int o = l; o < n * 72; o += 64) g[o] = stg[(o / 72) * 73 + (o % 72)];
        }
    }

    // ---- projection -> LDS -> coalesced store ----
    __syncthreads();
    if (act) {
        #pragma unroll
        for (int j = 0; j < NJ; ++j) {
            float px = pf[3*j+0], py = pf[3*j+1], pz = pf[3*j+2];
            float cx = A[0]*px + A[1]*py + A[2]*pz + tx;
            float cv = A[3]*px + A[4]*py + A[5]*pz + ty;
            float cz = A[6]*px + A[7]*py + A[8]*pz + tz;
            float zc = fmaxf(cz, 1e-5f);
            stg[l*73 + 2*j + 0] = (K00 * (cx / zc) + K02) * (2.0f / 512.0f) - 1.0f;
            stg[l*73 + 2*j + 1] = (K11 * (cv / zc) + K12) * (2.0f / 512.0f) - 1.0f;
        }
    }
    __syncthreads();
    {
        float* g = out_2d + (size_t)e0 * 48;
        if (n == 64) {
            float4* g4 = (float4*)g;
            #pragma unroll
            for (int it = 0; it < 12; ++it) {
                int i4 = l + it * 64;
                int o = i4 * 4;
                int base = (o / 48) * 73 + (o % 48);
                g4[i4] = make_float4(stg[base], stg[base+1], stg[base+2], stg[base+3]);
            }
        } else {
            for (int o = l; o < n * 48; o += 64) g[o] = stg[(o / 48) * 73 + (o % 48)];
        }
    }
}

// ================== Kernel 2: rots = rot_mats @ Ra, one thread per (b,j) ==================
__global__ __launch_bounds__(256)
void poseaug_rots_kernel(const float* __restrict__ rot_mats,
                         const float* __restrict__ axis,
                         const float* __restrict__ angle_u,
                         float* __restrict__ out_rots, long P)
{
    __shared__ __align__(16) float buf[2304];   // 256 pairs * 9 floats
    const int tb = threadIdx.x;
    const long T0 = (long)blockIdx.x * 256;
    const int cnt = (int)min((long)256, P - T0);
    const long t = T0 + tb;

    // ---- coop load rot_mats floats [9*T0, 9*T0+9*cnt) ----
    {
        const float* g = rot_mats + 9 * T0;
        if (cnt == 256) {
            const float4* g4 = (const float4*)g;   // 9*T0*4 B: T0 % 256 == 0 -> 16-aligned
            float4 v0 = g4[tb];
            float4 v1 = g4[tb + 256];
            *(float4*)&buf[tb * 4]         = v0;
            *(float4*)&buf[(tb + 256) * 4] = v1;
            if (tb < 64) {
                float4 v2 = g4[tb + 512];
                *(float4*)&buf[(tb + 512) * 4] = v2;
            }
        } else {
            for (int o = tb; o < cnt * 9; o += 256) buf[o] = g[o];
        }
    }
    __syncthreads();

    float m[9];
    float r[9];
    bool act = (tb < cnt);
    if (act) {
        #pragma unroll
        for (int k = 0; k < 9; ++k) m[k] = buf[tb * 9 + k];   // stride 9: conflict-free

        int j = (int)(t % 24);
        if (j == 0) {
            #pragma unroll
            for (int k = 0; k < 9; ++k) r[k] = m[k];
        } else {
            float ax = axis[3*t+0], ay = axis[3*t+1], az = axis[3*t+2];
            float Ra[9];
            make_Ra(ax, ay, az, angle_u[t], Ra);
            r[0] = m[0]*Ra[0] + m[1]*Ra[3] + m[2]*Ra[6];
            r[1] = m[0]*Ra[1] + m[1]*Ra[4] + m[2]*Ra[7];
            r[2] = m[0]*Ra[2] + m[1]*Ra[5] + m[2]*Ra[8];
            r[3] = m[3]*Ra[0] + m[4]*Ra[3] + m[5]*Ra[6];
            r[4] = m[3]*Ra[1] + m[4]*Ra[4] + m[5]*Ra[7];
            r[5] = m[3]*Ra[2] + m[4]*Ra[5] + m[5]*Ra[8];
            r[6] = m[6]*Ra[0] + m[7]*Ra[3] + m[8]*Ra[6];
            r[7] = m[6]*Ra[1] + m[7]*Ra[4] + m[8]*Ra[7];
            r[8] = m[6]*Ra[2] + m[7]*Ra[5] + m[8]*Ra[8];
        }
    }
    __syncthreads();     // all reads of buf done
    if (act) {
        #pragma unroll
        for (int k = 0; k < 9; ++k) buf[tb * 9 + k] = r[k];
    }
    __syncthreads();

    // ---- coop store ----
    {
        float* g = out_rots + 9 * T0;
        if (cnt == 256) {
            float4* g4 = (float4*)g;
            g4[tb]       = *(float4*)&buf[tb * 4];
            g4[tb + 256] = *(float4*)&buf[(tb + 256) * 4];
            if (tb < 64) g4[tb + 512] = *(float4*)&buf[(tb + 512) * 4];
        } else {
            for (int o = tb; o < cnt * 9; o += 256) g[o] = buf[o];
        }
    }
}

extern "C" void kernel_launch(void* const* d_in, const int* in_sizes, int n_in,
                              void* d_out, int out_size, void* d_ws, size_t ws_size,
                              hipStream_t stream) {
    const float* poses_3d = (const float*)d_in[0];
    const float* rot_mats = (const float*)d_in[1];
    const float* axis     = (const float*)d_in[2];
    const float* angle_u  = (const float*)d_in[3];
    const float* scale_u  = (const float*)d_in[4];
    const float* Kin      = (const float*)d_in[5];
    const float* Rin      = (const float*)d_in[6];
    const float* tin      = (const float*)d_in[7];
    const float* focal_u  = (const float*)d_in[8];
    const float* yaw_u    = (const float*)d_in[9];
    const float* pitch_u  = (const float*)d_in[10];
    const float* t_jit    = (const float*)d_in[11];
    float* out = (float*)d_out;

    const int B = in_sizes[9];   // yaw_u is (B,)
    float* out_rots = out + (size_t)B * 120;

    dim3 blk1(64), grd1((B + 63) / 64);
    hipLaunchKernelGGL(poseaug_chain_kernel, grd1, blk1, 0, stream,
                       poses_3d, axis, angle_u, scale_u, Kin, Rin, tin,
                       focal_u, yaw_u, pitch_u, t_jit, out, B);

    const long P = (long)B * NJ;
    dim3 blk2(256), grd2((unsigned)((P + 255) / 256));
    hipLaunchKernelGGL(poseaug_rots_kernel, grd2, blk2, 0, stream,
                       rot_mats, axis, angle_u, out_rots, P);
}